// Round 9
// baseline (30.828 us; speedup 1.0000x reference)
//
#include <hip/hip_runtime.h>
#include <hip/hip_bf16.h>
#include <cstddef>

#define N_NODES 100000
#define HIDDEN  128
#define N_EDGES 1600000
#define K2_BLOCKS 2048
#define K2_THREADS (K2_BLOCKS * 256)   // 524288 = exactly 32 waves/CU

typedef int   i32x2 __attribute__((ext_vector_type(2)));
typedef float f32x2 __attribute__((ext_vector_type(2)));
typedef float f32x4 __attribute__((ext_vector_type(4)));

__device__ __forceinline__ float dot8(const f32x4 a0, const f32x4 a1,
                                      const f32x4 b0, const f32x4 b1) {
    return a0.x * b0.x + a0.y * b0.y + a0.z * b0.z + a0.w * b0.w
         + a1.x * b1.x + a1.y * b1.y + a1.z * b1.z + a1.w * b1.w;
}

// Kernel 1: per-node dots. One wave owns 4 consecutive quads = 16 rows = 8KB.
// (measured near its 51.2MB stream floor)
__global__ __launch_bounds__(256) void node_dots_kernel(
        const float* __restrict__ x,
        const float* __restrict__ w,
        float* __restrict__ s_row,
        float* __restrict__ s_col) {
    const int tid = blockIdx.x * blockDim.x + threadIdx.x;
    const int wv  = tid >> 6;
    if (wv >= N_NODES / 16) return;
    const int lane = threadIdx.x & 63;
    const int sub  = lane & 15;
    const int rsub = lane >> 4;

    const f32x4 wr0 = *reinterpret_cast<const f32x4*>(w + 8 * sub);
    const f32x4 wr1 = *reinterpret_cast<const f32x4*>(w + 8 * sub + 4);
    const f32x4 wc0 = *reinterpret_cast<const f32x4*>(w + HIDDEN + 8 * sub);
    const f32x4 wc1 = *reinterpret_cast<const f32x4*>(w + HIDDEN + 8 * sub + 4);

    const int q0 = wv * 4;
    f32x4 v0[4], v1[4];
    #pragma unroll
    for (int k = 0; k < 4; ++k) {
        const float* xp = x + ((size_t)(q0 + k) * 4 + rsub) * HIDDEN + 8 * sub;
        v0[k] = *reinterpret_cast<const f32x4*>(xp);
        v1[k] = *reinterpret_cast<const f32x4*>(xp + 4);
    }

    #pragma unroll
    for (int k = 0; k < 4; ++k) {
        float pr = dot8(v0[k], v1[k], wr0, wr1);
        float pc = dot8(v0[k], v1[k], wc0, wc1);
        #pragma unroll
        for (int off = 8; off > 0; off >>= 1) {
            pr += __shfl_down(pr, off, 64);
            pc += __shfl_down(pc, off, 64);
        }
        if (sub == 0) {
            const int n = 4 * (q0 + k) + rsub;
            s_row[n] = pr;
            s_col[n] = pc;
        }
    }
}

// Kernel 2: out[e] = sigmoid(s_row[row[e]] + s_col[col[e]])
// 2048 blocks (exactly 32 waves/CU) x 2 units/thread (unit = 2 edges).
// All index loads issued first, then all 8 gathers together -> 2 latency
// chains total, 8+ outstanding gathers per thread at full TLP.
__global__ __launch_bounds__(256) void edge_sigmoid_kernel(
        const int* __restrict__ ei,
        const float* __restrict__ s_row,
        const float* __restrict__ s_col,
        float* __restrict__ out) {
    const int tid = blockIdx.x * blockDim.x + threadIdx.x;
    const int u0  = tid;                 // unit = pair of edges
    const int u1  = tid + K2_THREADS;
    const bool v1 = u1 < N_EDGES / 2;

    // stage 1: all index loads (independent, batched behind one wait)
    const i32x2 ra = *reinterpret_cast<const i32x2*>(ei + 2 * u0);
    const i32x2 ca = *reinterpret_cast<const i32x2*>(ei + N_EDGES + 2 * u0);
    i32x2 rb = {}, cb = {};
    if (v1) {
        rb = *reinterpret_cast<const i32x2*>(ei + 2 * u1);
        cb = *reinterpret_cast<const i32x2*>(ei + N_EDGES + 2 * u1);
    }

    // stage 2: all gathers (8 independent dword loads)
    const float a0 = s_row[ra.x], b0 = s_col[ca.x];
    const float a1 = s_row[ra.y], b1 = s_col[ca.y];
    float a2 = 0.f, b2 = 0.f, a3 = 0.f, b3 = 0.f;
    if (v1) {
        a2 = s_row[rb.x]; b2 = s_col[cb.x];
        a3 = s_row[rb.y]; b3 = s_col[cb.y];
    }

    // stage 3: compute + store
    f32x2 oa;
    oa.x = 1.0f / (1.0f + __expf(-(a0 + b0)));
    oa.y = 1.0f / (1.0f + __expf(-(a1 + b1)));
    __builtin_nontemporal_store(oa, reinterpret_cast<f32x2*>(out + 2 * u0));
    if (v1) {
        f32x2 ob;
        ob.x = 1.0f / (1.0f + __expf(-(a2 + b2)));
        ob.y = 1.0f / (1.0f + __expf(-(a3 + b3)));
        __builtin_nontemporal_store(ob, reinterpret_cast<f32x2*>(out + 2 * u1));
    }
}

extern "C" void kernel_launch(void* const* d_in, const int* in_sizes, int n_in,
                              void* d_out, int out_size, void* d_ws, size_t ws_size,
                              hipStream_t stream) {
    const int*   edge_index = (const int*)d_in[0];   // (2, N_EDGES) int32
    const float* x          = (const float*)d_in[1]; // (N_NODES, HIDDEN)
    const float* att_weight = (const float*)d_in[2]; // (1, 2*HIDDEN)
    float*       out        = (float*)d_out;         // (N_EDGES, 1)

    float* s_row = (float*)d_ws;           // N_NODES floats
    float* s_col = s_row + N_NODES;        // N_NODES floats

    // 6250 waves (4 quads each), 4 waves/block -> 1563 blocks
    node_dots_kernel<<<(N_NODES / 16 + 3) / 4, 256, 0, stream>>>(
        x, att_weight, s_row, s_col);

    // 2048 blocks, 2 pipelined units per thread
    edge_sigmoid_kernel<<<K2_BLOCKS, 256, 0, stream>>>(
        edge_index, s_row, s_col, out);
}